// Round 7
// baseline (1374.365 us; speedup 1.0000x reference)
//
#include <hip/hip_runtime.h>
#include <hip/hip_bf16.h>
#include <math.h>

// Problem constants (from setup_inputs)
#define BB 8
#define QN 512
#define SN 64
#define TN 128
#define DD 128
#define STAT_K 8
#define TOK_K 16
#define SCALE 0.08838834764831845f   // 1/sqrt(128)
#define NEGBIG -1e6f
#define NINF  -3.4e38f

typedef float f4 __attribute__((ext_vector_type(4)));
typedef float f2 __attribute__((ext_vector_type(2)));
typedef unsigned long long u64;

// ---------------------------------------------------------------------------
// LDS-free GEMM tile with explicit 2-stage pipeline: C[128-row-block] = A @ W.
// W read from L1/L2 (broadcast, 64 KB, cache-resident). 256 threads, 8x8 tile.
// ---------------------------------------------------------------------------
#define PLOAD(k0_, a_, wl_, wh_)                                              \
  { _Pragma("unroll")                                                         \
    for (int i_ = 0; i_ < 8; ++i_)                                            \
        a_[i_] = *(const f4*)(Ab + i_ * 128 + (k0_));                         \
    _Pragma("unroll")                                                         \
    for (int kk_ = 0; kk_ < 4; ++kk_) {                                       \
        wl_[kk_] = *(const f4*)(W + (size_t)((k0_) + kk_) * 128 + tx * 4);    \
        wh_[kk_] = *(const f4*)(W + (size_t)((k0_) + kk_) * 128 + 64 + tx * 4);\
    } }

#define PFMA(a_, wl_, wh_)                                                    \
  { _Pragma("unroll")                                                         \
    for (int i_ = 0; i_ < 8; ++i_)                                            \
        _Pragma("unroll")                                                     \
        for (int kk_ = 0; kk_ < 4; ++kk_)                                     \
            _Pragma("unroll")                                                 \
            for (int j_ = 0; j_ < 4; ++j_) {                                  \
                acc[i_][j_]     = fmaf(a_[i_][kk_], wl_[kk_][j_], acc[i_][j_]);\
                acc[i_][4 + j_] = fmaf(a_[i_][kk_], wh_[kk_][j_], acc[i_][4 + j_]);\
            } }

__device__ __forceinline__ void proj_tile8_g(const float* __restrict__ A,
                                             const float* __restrict__ W,
                                             float* __restrict__ C,
                                             int blk, int transposed, int tid)
{
    const int tx = tid & 15;    // cols tx*4..+3 and 64+tx*4..+3
    const int ty = tid >> 4;    // rows ty*8..+7
    const size_t rowBase = (size_t)blk * 128;
    const float* Ab = A + (rowBase + ty * 8) * 128;

    float acc[8][8];
    #pragma unroll
    for (int i = 0; i < 8; ++i)
        #pragma unroll
        for (int j = 0; j < 8; ++j) acc[i][j] = 0.f;

    f4 aA[8], wlA[4], whA[4];
    f4 aB[8], wlB[4], whB[4];
    PLOAD(0, aA, wlA, whA);
    #pragma unroll
    for (int k0 = 0; k0 < 128; k0 += 8) {
        PLOAD(k0 + 4, aB, wlB, whB);
        PFMA(aA, wlA, whA);
        if (k0 + 8 < 128) PLOAD(k0 + 8, aA, wlA, whA);
        PFMA(aB, wlB, whB);
    }

    if (!transposed) {
        #pragma unroll
        for (int i = 0; i < 8; ++i) {
            size_t row = rowBase + ty * 8 + i;
            f4 lo = {acc[i][0], acc[i][1], acc[i][2], acc[i][3]};
            f4 hi = {acc[i][4], acc[i][5], acc[i][6], acc[i][7]};
            *(f4*)&C[row * 128 + tx * 4]      = lo;
            *(f4*)&C[row * 128 + 64 + tx * 4] = hi;
        }
    } else {
        float* Cb = C + ((size_t)blk << 14);   // per-(b,s) [d][t] block
        #pragma unroll
        for (int j = 0; j < 4; ++j) {
            int clo = tx * 4 + j;
            int chi = 64 + tx * 4 + j;
            f4 v0 = {acc[0][j], acc[1][j], acc[2][j], acc[3][j]};
            f4 v1 = {acc[4][j], acc[5][j], acc[6][j], acc[7][j]};
            *(f4*)&Cb[clo * 128 + ty * 8]     = v0;
            *(f4*)&Cb[clo * 128 + ty * 8 + 4] = v1;
            f4 v2 = {acc[0][4 + j], acc[1][4 + j], acc[2][4 + j], acc[3][4 + j]};
            f4 v3 = {acc[4][4 + j], acc[5][4 + j], acc[6][4 + j], acc[7][4 + j]};
            *(f4*)&Cb[chi * 128 + ty * 8]     = v2;
            *(f4*)&Cb[chi * 128 + ty * 8 + 4] = v3;
        }
    }
}

// Input projections + the Wv@Wo fold, one launch. values projection is GONE:
// PV runs on raw values and the output projection uses M_vo = Wv @ Wo
// (mathematically identical — combine is linear; no selection risk).
__global__ __launch_bounds__(256) void proj_all(const float* __restrict__ queries,
                                                const float* __restrict__ stat_keys,
                                                const float* __restrict__ token_keys,
                                                const float* __restrict__ Wq_stat,
                                                const float* __restrict__ Wq_token,
                                                const float* __restrict__ Wk_stat,
                                                const float* __restrict__ Wk_token,
                                                const float* __restrict__ Wv,
                                                const float* __restrict__ Wo,
                                                float* __restrict__ q_stat,
                                                float* __restrict__ q_tok,
                                                float* __restrict__ k_stat,
                                                float* __restrict__ kT,
                                                float* __restrict__ M_vo)
{
    const int bi = blockIdx.x;
    if (bi < 512)       proj_tile8_g(token_keys, Wk_token, kT,     bi,       1, threadIdx.x);
    else if (bi < 544)  proj_tile8_g(queries,    Wq_stat,  q_stat, bi - 512, 0, threadIdx.x);
    else if (bi < 576)  proj_tile8_g(queries,    Wq_token, q_tok,  bi - 544, 0, threadIdx.x);
    else if (bi < 580)  proj_tile8_g(stat_keys,  Wk_stat,  k_stat, bi - 576, 0, threadIdx.x);
    else                proj_tile8_g(Wv,         Wo,       M_vo,   0,        0, threadIdx.x);
}

// Output projection: out = out_pre @ M_vo. 64 rows/block.
__global__ __launch_bounds__(256) void proj_out(const float* __restrict__ A,
                                                const float* __restrict__ W,
                                                float* __restrict__ C)
{
    const int tid = threadIdx.x;
    const int tx = tid & 15;
    const int ty = tid >> 4;
    const int rowBase = blockIdx.x * 64 + ty * 4;
    const float* Ab = A + (size_t)rowBase * 128;

    float acc[4][8];
    #pragma unroll
    for (int i = 0; i < 4; ++i)
        #pragma unroll
        for (int j = 0; j < 8; ++j) acc[i][j] = 0.f;

    #pragma unroll 2
    for (int k0 = 0; k0 < 128; k0 += 4) {
        f4 a[4];
        #pragma unroll
        for (int i = 0; i < 4; ++i)
            a[i] = *(const f4*)(Ab + i * 128 + k0);
        f4 wl[4], wh[4];
        #pragma unroll
        for (int kk = 0; kk < 4; ++kk) {
            wl[kk] = *(const f4*)(W + (k0 + kk) * 128 + tx * 4);
            wh[kk] = *(const f4*)(W + (k0 + kk) * 128 + 64 + tx * 4);
        }
        #pragma unroll
        for (int i = 0; i < 4; ++i)
            #pragma unroll
            for (int kk = 0; kk < 4; ++kk)
                #pragma unroll
                for (int j = 0; j < 4; ++j) {
                    acc[i][j]     = fmaf(a[i][kk], wl[kk][j], acc[i][j]);
                    acc[i][4 + j] = fmaf(a[i][kk], wh[kk][j], acc[i][4 + j]);
                }
    }
    #pragma unroll
    for (int i = 0; i < 4; ++i) {
        size_t row = (size_t)rowBase + i;
        f4 lo = {acc[i][0], acc[i][1], acc[i][2], acc[i][3]};
        f4 hi = {acc[i][4], acc[i][5], acc[i][6], acc[i][7]};
        *(f4*)&C[row * 128 + tx * 4]      = lo;
        *(f4*)&C[row * 128 + 64 + tx * 4] = hi;
    }
}

// ---------------------------------------------------------------------------
// Stat level: one wave per (b,q), lane = stat s. Top-8 + softmax (exact jax
// tie-break). Invalid stats -> exp underflows to exactly 0. (proven R1)
// ---------------------------------------------------------------------------
__global__ __launch_bounds__(64, 4) void stat_topk(const float* __restrict__ qs,
                                                   const float* __restrict__ ks,
                                                   const int* __restrict__ vlen,
                                                   int* __restrict__ sel_i,
                                                   float* __restrict__ sel_w)
{
    const int bq   = blockIdx.x;
    const int b    = bq >> 9;
    const int lane = threadIdx.x;

    const f4* q4 = (const f4*)(qs + (size_t)bq * 128);
    const f4* k4 = (const f4*)(ks + (size_t)(b * SN + lane) * 128);
    float acc = 0.f;
    #pragma unroll 8
    for (int kk = 0; kk < 32; ++kk) {
        f4 q = q4[kk];
        f4 k = k4[kk];
        acc = fmaf(q[0], k[0], acc);
        acc = fmaf(q[1], k[1], acc);
        acc = fmaf(q[2], k[2], acc);
        acc = fmaf(q[3], k[3], acc);
    }
    float score = acc * SCALE;
    if (lane >= vlen[b]) score = NEGBIG;

    float work = score;
    float tv[STAT_K];
    int   ti[STAT_K];
    #pragma unroll
    for (int j = 0; j < STAT_K; ++j) {
        float m = work;
        #pragma unroll
        for (int off = 32; off > 0; off >>= 1) m = fmaxf(m, __shfl_xor(m, off));
        unsigned long long ball = __ballot(work == m);
        int L = __ffsll(ball) - 1;     // lowest index wins ties
        tv[j] = m;
        ti[j] = L;
        if (lane == L) work = NINF;
    }

    float w[STAT_K];
    float Z = 0.f;
    #pragma unroll
    for (int j = 0; j < STAT_K; ++j) { w[j] = expf(tv[j] - tv[0]); Z += w[j]; }
    float invZ = 1.f / Z;

    if (lane < STAT_K) {
        sel_i[(size_t)bq * STAT_K + lane] = ti[lane];
        sel_w[(size_t)bq * STAT_K + lane] = w[lane] * invZ;
    }
}

// ---------------------------------------------------------------------------
__global__ void zero_cnt(int* __restrict__ cnt)
{
    int idx = blockIdx.x * 256 + threadIdx.x;
    if (idx < BB * SN) cnt[idx] = 0;
}

__global__ void bin_build(const int* __restrict__ sel_i,
                          const float* __restrict__ sel_w,
                          int* __restrict__ cnt, int* __restrict__ list)
{
    int idx = blockIdx.x * 256 + threadIdx.x;    // bq*8+si, 32768 total
    if (idx >= BB * QN * STAT_K) return;
    float sw = sel_w[idx];
    if (sw == 0.f) return;                       // exactly-zero contribution
    int bq = idx >> 3, si = idx & 7;
    int b = bq >> 9, q = bq & 511;
    int s = sel_i[idx];
    int bs = b * SN + s;
    int pos = atomicAdd(&cnt[bs], 1);
    list[bs * 512 + pos] = q | (si << 16);
}

// ---------------------------------------------------------------------------
// K1: token scores as a plain GEMM (pipelined). Block = (bin, 64-pair chunk).
// scores[pid][t] = q_tok[bq] . kT[bs][.][t] * SCALE
// ---------------------------------------------------------------------------
#define TLOAD(k0_, a_, wl_, wh_)                                              \
  { _Pragma("unroll")                                                         \
    for (int i_ = 0; i_ < 4; ++i_)                                            \
        a_[i_] = *(const f4*)(Ab[i_] + (k0_));                                \
    _Pragma("unroll")                                                         \
    for (int kk_ = 0; kk_ < 4; ++kk_) {                                       \
        wl_[kk_] = *(const f4*)(kb + (size_t)((k0_) + kk_) * 128 + tx * 4);   \
        wh_[kk_] = *(const f4*)(kb + (size_t)((k0_) + kk_) * 128 + 64 + tx * 4);\
    } }

#define TFMA(a_, wl_, wh_)                                                    \
  { _Pragma("unroll")                                                         \
    for (int i_ = 0; i_ < 4; ++i_)                                            \
        _Pragma("unroll")                                                     \
        for (int kk_ = 0; kk_ < 4; ++kk_)                                     \
            _Pragma("unroll")                                                 \
            for (int j_ = 0; j_ < 4; ++j_) {                                  \
                acc[i_][j_]     = fmaf(a_[i_][kk_], wl_[kk_][j_], acc[i_][j_]);\
                acc[i_][4 + j_] = fmaf(a_[i_][kk_], wh_[kk_][j_], acc[i_][4 + j_]);\
            } }

__global__ __launch_bounds__(256) void tok_score(const float* __restrict__ qt,
                                                 const float* __restrict__ kT,
                                                 const int* __restrict__ cnt,
                                                 const int* __restrict__ list,
                                                 float* __restrict__ scores)
{
    const int bin   = blockIdx.x & 511;
    const int chunk = blockIdx.x >> 9;
    const int b  = bin & 7;            // batch fast -> XCD spread
    const int s  = bin >> 3;
    const int bs = b * SN + s;
    const int nq = cnt[bs];
    const int q0 = chunk * 64;
    if (q0 >= nq) return;

    const int tid = threadIdx.x;
    const int tx = tid & 15;           // t-cols tx*4..+3 and 64+tx*4..+3
    const int ty = tid >> 4;           // pair-slots q0+ty*4..+3

    int pid[4];
    const float* Ab[4];
    #pragma unroll
    for (int i = 0; i < 4; ++i) {
        int e  = list[bs * 512 + min(q0 + ty * 4 + i, nq - 1)];  // clamp: dup pair
        int q  = e & 0xffff;
        int si = (e >> 16) & 7;
        pid[i] = ((b << 9) + q) * 8 + si;
        Ab[i]  = qt + ((size_t)(b << 9) + q) * 128;
    }
    const float* kb = kT + ((size_t)bs << 14);

    float acc[4][8];
    #pragma unroll
    for (int i = 0; i < 4; ++i)
        #pragma unroll
        for (int j = 0; j < 8; ++j) acc[i][j] = 0.f;

    f4 aA[4], wlA[4], whA[4];
    f4 aB[4], wlB[4], whB[4];
    TLOAD(0, aA, wlA, whA);
    #pragma unroll
    for (int k0 = 0; k0 < 128; k0 += 8) {
        TLOAD(k0 + 4, aB, wlB, whB);
        TFMA(aA, wlA, whA);
        if (k0 + 8 < 128) TLOAD(k0 + 8, aA, wlA, whA);
        TFMA(aB, wlB, whB);
    }

    #pragma unroll
    for (int i = 0; i < 4; ++i) {
        float* out = scores + (size_t)pid[i] * 128;
        f4 lo = {acc[i][0] * SCALE, acc[i][1] * SCALE, acc[i][2] * SCALE, acc[i][3] * SCALE};
        f4 hi = {acc[i][4] * SCALE, acc[i][5] * SCALE, acc[i][6] * SCALE, acc[i][7] * SCALE};
        *(f4*)(out + tx * 4)      = lo;    // dup pids write identical data: benign
        *(f4*)(out + 64 + tx * 4) = hi;
    }
}

// ---------------------------------------------------------------------------
// K2: exact top-16 + softmax weights per pair. One wave per pid.
// Lane holds tokens 2*lane, 2*lane+1 -> exact jax tie-break (lowest index).
// ---------------------------------------------------------------------------
__global__ __launch_bounds__(256) void tok_select(const float* __restrict__ scores,
                                                  const float* __restrict__ sel_w,
                                                  int* __restrict__ pvt,
                                                  float* __restrict__ pvw)
{
    const int pid  = blockIdx.x * 4 + (threadIdx.x >> 6);
    const int lane = threadIdx.x & 63;

    float sw = sel_w[pid];
    if (sw == 0.f) {                        // never binned: zero contribution
        if (lane < TOK_K) {
            pvt[(size_t)pid * TOK_K + lane] = 0;
            pvw[(size_t)pid * TOK_K + lane] = 0.f;
        }
        return;
    }

    f2 c = *(const f2*)(scores + (size_t)pid * 128 + lane * 2);
    float c0 = c[0], c1 = c[1];

    float tv[TOK_K];
    int   tt[TOK_K];
    #pragma unroll
    for (int j = 0; j < TOK_K; ++j) {
        float lm = fmaxf(c0, c1);
        float m = lm;
        #pragma unroll
        for (int off = 32; off > 0; off >>= 1) m = fmaxf(m, __shfl_xor(m, off));
        u64 b0 = __ballot(c0 == m);
        u64 b1 = __ballot(c1 == m);
        int L0 = b0 ? (__ffsll(b0) - 1) : 64;
        int L1 = b1 ? (__ffsll(b1) - 1) : 64;
        int t0 = 2 * L0, t1 = 2 * L1 + 1;
        int t  = min(t0, t1);               // lowest token index among ties
        tv[j] = m;
        tt[j] = t;
        if (lane == (t >> 1)) {
            if (t & 1) c1 = NINF; else c0 = NINF;
        }
    }

    float m0 = tv[0];
    float Z = 0.f;
    float pw[TOK_K];
    #pragma unroll
    for (int j = 0; j < TOK_K; ++j) { pw[j] = expf(tv[j] - m0); Z += pw[j]; }
    float cs = sw / Z;                      // fold stat weight in

    if (lane < TOK_K) {
        pvt[(size_t)pid * TOK_K + lane] = tt[lane];
        pvw[(size_t)pid * TOK_K + lane] = pw[lane] * cs;
    }
}

// ---------------------------------------------------------------------------
// K3: PV accumulate over RAW values (Wv folded into M_vo). One wave per (b,q),
// registers only, single plain store (no atomics -> deterministic).
// ---------------------------------------------------------------------------
__global__ __launch_bounds__(256) void tok_pv2(const float* __restrict__ values,
                                               const int* __restrict__ sel_i,
                                               const int* __restrict__ pvt,
                                               const float* __restrict__ pvw,
                                               float* __restrict__ out_pre)
{
    const int bq   = blockIdx.x * 4 + (threadIdx.x >> 6);
    const int lane = threadIdx.x & 63;
    const int b    = bq >> 9;

    float o0 = 0.f, o1 = 0.f;
    #pragma unroll
    for (int si = 0; si < STAT_K; ++si) {
        const int pid = bq * STAT_K + si;
        const int s   = sel_i[pid];
        const float* vb = values + ((size_t)(b * SN + s) << 14);
        const int*   tp = pvt + (size_t)pid * TOK_K;
        const float* wp = pvw + (size_t)pid * TOK_K;
        #pragma unroll
        for (int j = 0; j < TOK_K; ++j) {
            int   t = tp[j];                 // wave-uniform
            float w = wp[j];                 // ==0 for skipped pids: exact no-op
            f2 x = *(const f2*)(vb + (size_t)t * 128 + lane * 2);
            o0 = fmaf(w, x[0], o0);
            o1 = fmaf(w, x[1], o1);
        }
    }
    f2 o = {o0, o1};
    *(f2*)(out_pre + (size_t)bq * 128 + lane * 2) = o;
}

// ---------------------------------------------------------------------------
extern "C" void kernel_launch(void* const* d_in, const int* in_sizes, int n_in,
                              void* d_out, int out_size, void* d_ws, size_t ws_size,
                              hipStream_t stream)
{
    const float* queries    = (const float*)d_in[0];
    const float* stat_keys  = (const float*)d_in[1];
    const float* token_keys = (const float*)d_in[2];
    const float* values     = (const float*)d_in[3];
    const int*   vlen       = (const int*)d_in[4];
    const float* Wq_stat    = (const float*)d_in[5];
    const float* Wq_token   = (const float*)d_in[6];
    const float* Wk_stat    = (const float*)d_in[7];
    const float* Wk_token   = (const float*)d_in[8];
    const float* Wv         = (const float*)d_in[9];
    const float* Wo         = (const float*)d_in[10];

    char* ws = (char*)d_ws;
    float* q_stat  = (float*)(ws);                 // 2 MB (dead after stat_topk)
    int*   list    = (int*)  (ws);                 // 1 MB, overlays q_stat
    float* q_tok   = (float*)(ws + 2097152);       // 2 MB (live till tok_score)
    float* k_stat  = (float*)(ws + 4194304);       // 256 KB (dead after stat_topk)
    int*   cnt     = (int*)  (ws + 4194304);       // 2 KB, overlays k_stat
    float* M_vo    = (float*)(ws + 4456448);       // 64 KB (Wv @ Wo)
    int*   sel_i   = (int*)  (ws + 4521984);       // 128 KB
    float* sel_w   = (float*)(ws + 4653056);       // 128 KB
    float* kT      = (float*)(ws + 4784128);       // 32 MB (dead after tok_score)
    float* scores  = (float*)(ws + 38338560);      // 16 MB
    int*   pvt     = (int*)  (ws + 55115776);      // 2 MB
    float* pvw     = (float*)(ws + 57212928);      // 2 MB
    float* out_pre = (float*)(ws + 59310080);      // 2 MB   (total ~61.4 MB)

    // Projections feeding selection (fp32 exact) + the safe Wv@Wo fold
    proj_all<<<581, 256, 0, stream>>>(queries, stat_keys, token_keys,
                                      Wq_stat, Wq_token, Wk_stat, Wk_token, Wv, Wo,
                                      q_stat, q_tok, k_stat, kT, M_vo);

    // Stat-level top-8 selection + weights
    stat_topk<<<BB * QN, 64, 0, stream>>>(q_stat, k_stat, vlen, sel_i, sel_w);

    // Zero bin counters (overlays dead k_stat), bin (q,si) pairs by stat
    zero_cnt<<<2, 256, 0, stream>>>(cnt);
    bin_build<<<128, 256, 0, stream>>>(sel_i, sel_w, cnt, list);

    // K1: token scores (GEMM shape, k read once per chunk from L2)
    tok_score<<<4096, 256, 0, stream>>>(q_tok, kT, cnt, list, scores);

    // K2: exact top-16 + folded softmax weights, one wave per pair
    tok_select<<<BB * QN * STAT_K / 4, 256, 0, stream>>>(scores, sel_w, pvt, pvw);

    // K3: PV accumulate on RAW values, one wave per (b,q), no atomics
    tok_pv2<<<BB * QN / 4, 256, 0, stream>>>(values, sel_i, pvt, pvw, out_pre);

    // Output projection with folded M_vo
    proj_out<<<64, 256, 0, stream>>>(out_pre, M_vo, (float*)d_out);
}

// Round 8
// 1357.481 us; speedup vs baseline: 1.0124x; 1.0124x over previous
//
#include <hip/hip_runtime.h>
#include <hip/hip_bf16.h>
#include <math.h>

// Problem constants (from setup_inputs)
#define BB 8
#define QN 512
#define SN 64
#define TN 128
#define DD 128
#define STAT_K 8
#define TOK_K 16
#define SCALE 0.08838834764831845f   // 1/sqrt(128)
#define NEGBIG -1e6f
#define NINF  -3.4e38f

typedef float f4 __attribute__((ext_vector_type(4)));
typedef float f2 __attribute__((ext_vector_type(2)));
typedef unsigned long long u64;

// ---------------------------------------------------------------------------
// LDS-free GEMM tile with explicit 2-stage pipeline: C[128-row-block] = A @ W.
// W read from L1/L2 (broadcast, 64 KB, cache-resident). 256 threads, 8x8 tile.
// ---------------------------------------------------------------------------
#define PLOAD(k0_, a_, wl_, wh_)                                              \
  { _Pragma("unroll")                                                         \
    for (int i_ = 0; i_ < 8; ++i_)                                            \
        a_[i_] = *(const f4*)(Ab + i_ * 128 + (k0_));                         \
    _Pragma("unroll")                                                         \
    for (int kk_ = 0; kk_ < 4; ++kk_) {                                       \
        wl_[kk_] = *(const f4*)(W + (size_t)((k0_) + kk_) * 128 + tx * 4);    \
        wh_[kk_] = *(const f4*)(W + (size_t)((k0_) + kk_) * 128 + 64 + tx * 4);\
    } }

#define PFMA(a_, wl_, wh_)                                                    \
  { _Pragma("unroll")                                                         \
    for (int i_ = 0; i_ < 8; ++i_)                                            \
        _Pragma("unroll")                                                     \
        for (int kk_ = 0; kk_ < 4; ++kk_)                                     \
            _Pragma("unroll")                                                 \
            for (int j_ = 0; j_ < 4; ++j_) {                                  \
                acc[i_][j_]     = fmaf(a_[i_][kk_], wl_[kk_][j_], acc[i_][j_]);\
                acc[i_][4 + j_] = fmaf(a_[i_][kk_], wh_[kk_][j_], acc[i_][4 + j_]);\
            } }

__device__ __forceinline__ void proj_tile8_g(const float* __restrict__ A,
                                             const float* __restrict__ W,
                                             float* __restrict__ C,
                                             int blk, int transposed, int tid)
{
    const int tx = tid & 15;    // cols tx*4..+3 and 64+tx*4..+3
    const int ty = tid >> 4;    // rows ty*8..+7
    const size_t rowBase = (size_t)blk * 128;
    const float* Ab = A + (rowBase + ty * 8) * 128;

    float acc[8][8];
    #pragma unroll
    for (int i = 0; i < 8; ++i)
        #pragma unroll
        for (int j = 0; j < 8; ++j) acc[i][j] = 0.f;

    f4 aA[8], wlA[4], whA[4];
    f4 aB[8], wlB[4], whB[4];
    PLOAD(0, aA, wlA, whA);
    #pragma unroll
    for (int k0 = 0; k0 < 128; k0 += 8) {
        PLOAD(k0 + 4, aB, wlB, whB);
        PFMA(aA, wlA, whA);
        if (k0 + 8 < 128) PLOAD(k0 + 8, aA, wlA, whA);
        PFMA(aB, wlB, whB);
    }

    if (!transposed) {
        #pragma unroll
        for (int i = 0; i < 8; ++i) {
            size_t row = rowBase + ty * 8 + i;
            f4 lo = {acc[i][0], acc[i][1], acc[i][2], acc[i][3]};
            f4 hi = {acc[i][4], acc[i][5], acc[i][6], acc[i][7]};
            *(f4*)&C[row * 128 + tx * 4]      = lo;
            *(f4*)&C[row * 128 + 64 + tx * 4] = hi;
        }
    } else {
        float* Cb = C + ((size_t)blk << 14);   // per-(b,s) [d][t] block
        #pragma unroll
        for (int j = 0; j < 4; ++j) {
            int clo = tx * 4 + j;
            int chi = 64 + tx * 4 + j;
            f4 v0 = {acc[0][j], acc[1][j], acc[2][j], acc[3][j]};
            f4 v1 = {acc[4][j], acc[5][j], acc[6][j], acc[7][j]};
            *(f4*)&Cb[clo * 128 + ty * 8]     = v0;
            *(f4*)&Cb[clo * 128 + ty * 8 + 4] = v1;
            f4 v2 = {acc[0][4 + j], acc[1][4 + j], acc[2][4 + j], acc[3][4 + j]};
            f4 v3 = {acc[4][4 + j], acc[5][4 + j], acc[6][4 + j], acc[7][4 + j]};
            *(f4*)&Cb[chi * 128 + ty * 8]     = v2;
            *(f4*)&Cb[chi * 128 + ty * 8 + 4] = v3;
        }
    }
}

// Input projections + the Wv@Wo fold, one launch. values projection is GONE:
// PV runs on raw values and the output projection uses M_vo = Wv @ Wo
// (mathematically identical — combine is linear; no selection risk).
__global__ __launch_bounds__(256) void proj_all(const float* __restrict__ queries,
                                                const float* __restrict__ stat_keys,
                                                const float* __restrict__ token_keys,
                                                const float* __restrict__ Wq_stat,
                                                const float* __restrict__ Wq_token,
                                                const float* __restrict__ Wk_stat,
                                                const float* __restrict__ Wk_token,
                                                const float* __restrict__ Wv,
                                                const float* __restrict__ Wo,
                                                float* __restrict__ q_stat,
                                                float* __restrict__ q_tok,
                                                float* __restrict__ k_stat,
                                                float* __restrict__ kT,
                                                float* __restrict__ M_vo)
{
    const int bi = blockIdx.x;
    if (bi < 512)       proj_tile8_g(token_keys, Wk_token, kT,     bi,       1, threadIdx.x);
    else if (bi < 544)  proj_tile8_g(queries,    Wq_stat,  q_stat, bi - 512, 0, threadIdx.x);
    else if (bi < 576)  proj_tile8_g(queries,    Wq_token, q_tok,  bi - 544, 0, threadIdx.x);
    else if (bi < 580)  proj_tile8_g(stat_keys,  Wk_stat,  k_stat, bi - 576, 0, threadIdx.x);
    else                proj_tile8_g(Wv,         Wo,       M_vo,   0,        0, threadIdx.x);
}

// Output projection: out = out_pre @ M_vo. 64 rows/block.
__global__ __launch_bounds__(256) void proj_out(const float* __restrict__ A,
                                                const float* __restrict__ W,
                                                float* __restrict__ C)
{
    const int tid = threadIdx.x;
    const int tx = tid & 15;
    const int ty = tid >> 4;
    const int rowBase = blockIdx.x * 64 + ty * 4;
    const float* Ab = A + (size_t)rowBase * 128;

    float acc[4][8];
    #pragma unroll
    for (int i = 0; i < 4; ++i)
        #pragma unroll
        for (int j = 0; j < 8; ++j) acc[i][j] = 0.f;

    #pragma unroll 2
    for (int k0 = 0; k0 < 128; k0 += 4) {
        f4 a[4];
        #pragma unroll
        for (int i = 0; i < 4; ++i)
            a[i] = *(const f4*)(Ab + i * 128 + k0);
        f4 wl[4], wh[4];
        #pragma unroll
        for (int kk = 0; kk < 4; ++kk) {
            wl[kk] = *(const f4*)(W + (k0 + kk) * 128 + tx * 4);
            wh[kk] = *(const f4*)(W + (k0 + kk) * 128 + 64 + tx * 4);
        }
        #pragma unroll
        for (int i = 0; i < 4; ++i)
            #pragma unroll
            for (int kk = 0; kk < 4; ++kk)
                #pragma unroll
                for (int j = 0; j < 4; ++j) {
                    acc[i][j]     = fmaf(a[i][kk], wl[kk][j], acc[i][j]);
                    acc[i][4 + j] = fmaf(a[i][kk], wh[kk][j], acc[i][4 + j]);
                }
    }
    #pragma unroll
    for (int i = 0; i < 4; ++i) {
        size_t row = (size_t)rowBase + i;
        f4 lo = {acc[i][0], acc[i][1], acc[i][2], acc[i][3]};
        f4 hi = {acc[i][4], acc[i][5], acc[i][6], acc[i][7]};
        *(f4*)&C[row * 128 + tx * 4]      = lo;
        *(f4*)&C[row * 128 + 64 + tx * 4] = hi;
    }
}

// ---------------------------------------------------------------------------
// Stat level: one wave per (b,q), lane = stat s. Top-8 + softmax (exact jax
// tie-break). Invalid stats -> exp underflows to exactly 0. (proven R1)
// ---------------------------------------------------------------------------
__global__ __launch_bounds__(64, 4) void stat_topk(const float* __restrict__ qs,
                                                   const float* __restrict__ ks,
                                                   const int* __restrict__ vlen,
                                                   int* __restrict__ sel_i,
                                                   float* __restrict__ sel_w)
{
    const int bq   = blockIdx.x;
    const int b    = bq >> 9;
    const int lane = threadIdx.x;

    const f4* q4 = (const f4*)(qs + (size_t)bq * 128);
    const f4* k4 = (const f4*)(ks + (size_t)(b * SN + lane) * 128);
    float acc = 0.f;
    #pragma unroll 8
    for (int kk = 0; kk < 32; ++kk) {
        f4 q = q4[kk];
        f4 k = k4[kk];
        acc = fmaf(q[0], k[0], acc);
        acc = fmaf(q[1], k[1], acc);
        acc = fmaf(q[2], k[2], acc);
        acc = fmaf(q[3], k[3], acc);
    }
    float score = acc * SCALE;
    if (lane >= vlen[b]) score = NEGBIG;

    float work = score;
    float tv[STAT_K];
    int   ti[STAT_K];
    #pragma unroll
    for (int j = 0; j < STAT_K; ++j) {
        float m = work;
        #pragma unroll
        for (int off = 32; off > 0; off >>= 1) m = fmaxf(m, __shfl_xor(m, off));
        unsigned long long ball = __ballot(work == m);
        int L = __ffsll(ball) - 1;     // lowest index wins ties
        tv[j] = m;
        ti[j] = L;
        if (lane == L) work = NINF;
    }

    float w[STAT_K];
    float Z = 0.f;
    #pragma unroll
    for (int j = 0; j < STAT_K; ++j) { w[j] = expf(tv[j] - tv[0]); Z += w[j]; }
    float invZ = 1.f / Z;

    if (lane < STAT_K) {
        sel_i[(size_t)bq * STAT_K + lane] = ti[lane];
        sel_w[(size_t)bq * STAT_K + lane] = w[lane] * invZ;
    }
}

// ---------------------------------------------------------------------------
__global__ void zero_cnt(int* __restrict__ cnt)
{
    int idx = blockIdx.x * 256 + threadIdx.x;
    if (idx < BB * SN) cnt[idx] = 0;
}

__global__ void bin_build(const int* __restrict__ sel_i,
                          const float* __restrict__ sel_w,
                          int* __restrict__ cnt, int* __restrict__ list)
{
    int idx = blockIdx.x * 256 + threadIdx.x;    // bq*8+si, 32768 total
    if (idx >= BB * QN * STAT_K) return;
    float sw = sel_w[idx];
    if (sw == 0.f) return;                       // exactly-zero contribution
    int bq = idx >> 3, si = idx & 7;
    int b = bq >> 9, q = bq & 511;
    int s = sel_i[idx];
    int bs = b * SN + s;
    int pos = atomicAdd(&cnt[bs], 1);
    list[bs * 512 + pos] = q | (si << 16);
}

// ---------------------------------------------------------------------------
// K1: token scores as a plain GEMM (pipelined). Block = (bin, 64-pair chunk).
// scores[pid][t] = q_tok[bq] . kT[bs][.][t] * SCALE
// ---------------------------------------------------------------------------
#define TLOAD(k0_, a_, wl_, wh_)                                              \
  { _Pragma("unroll")                                                         \
    for (int i_ = 0; i_ < 4; ++i_)                                            \
        a_[i_] = *(const f4*)(Ab[i_] + (k0_));                                \
    _Pragma("unroll")                                                         \
    for (int kk_ = 0; kk_ < 4; ++kk_) {                                       \
        wl_[kk_] = *(const f4*)(kb + (size_t)((k0_) + kk_) * 128 + tx * 4);   \
        wh_[kk_] = *(const f4*)(kb + (size_t)((k0_) + kk_) * 128 + 64 + tx * 4);\
    } }

#define TFMA(a_, wl_, wh_)                                                    \
  { _Pragma("unroll")                                                         \
    for (int i_ = 0; i_ < 4; ++i_)                                            \
        _Pragma("unroll")                                                     \
        for (int kk_ = 0; kk_ < 4; ++kk_)                                     \
            _Pragma("unroll")                                                 \
            for (int j_ = 0; j_ < 4; ++j_) {                                  \
                acc[i_][j_]     = fmaf(a_[i_][kk_], wl_[kk_][j_], acc[i_][j_]);\
                acc[i_][4 + j_] = fmaf(a_[i_][kk_], wh_[kk_][j_], acc[i_][4 + j_]);\
            } }

__global__ __launch_bounds__(256) void tok_score(const float* __restrict__ qt,
                                                 const float* __restrict__ kT,
                                                 const int* __restrict__ cnt,
                                                 const int* __restrict__ list,
                                                 float* __restrict__ scores)
{
    const int bin   = blockIdx.x & 511;
    const int chunk = blockIdx.x >> 9;
    const int b  = bin & 7;            // batch fast -> XCD spread
    const int s  = bin >> 3;
    const int bs = b * SN + s;
    const int nq = cnt[bs];
    const int q0 = chunk * 64;
    if (q0 >= nq) return;

    const int tid = threadIdx.x;
    const int tx = tid & 15;           // t-cols tx*4..+3 and 64+tx*4..+3
    const int ty = tid >> 4;           // pair-slots q0+ty*4..+3

    int pid[4];
    const float* Ab[4];
    #pragma unroll
    for (int i = 0; i < 4; ++i) {
        int e  = list[bs * 512 + min(q0 + ty * 4 + i, nq - 1)];  // clamp: dup pair
        int q  = e & 0xffff;
        int si = (e >> 16) & 7;
        pid[i] = ((b << 9) + q) * 8 + si;
        Ab[i]  = qt + ((size_t)(b << 9) + q) * 128;
    }
    const float* kb = kT + ((size_t)bs << 14);

    float acc[4][8];
    #pragma unroll
    for (int i = 0; i < 4; ++i)
        #pragma unroll
        for (int j = 0; j < 8; ++j) acc[i][j] = 0.f;

    f4 aA[4], wlA[4], whA[4];
    f4 aB[4], wlB[4], whB[4];
    TLOAD(0, aA, wlA, whA);
    #pragma unroll
    for (int k0 = 0; k0 < 128; k0 += 8) {
        TLOAD(k0 + 4, aB, wlB, whB);
        TFMA(aA, wlA, whA);
        if (k0 + 8 < 128) TLOAD(k0 + 8, aA, wlA, whA);
        TFMA(aB, wlB, whB);
    }

    #pragma unroll
    for (int i = 0; i < 4; ++i) {
        float* out = scores + (size_t)pid[i] * 128;
        f4 lo = {acc[i][0] * SCALE, acc[i][1] * SCALE, acc[i][2] * SCALE, acc[i][3] * SCALE};
        f4 hi = {acc[i][4] * SCALE, acc[i][5] * SCALE, acc[i][6] * SCALE, acc[i][7] * SCALE};
        *(f4*)(out + tx * 4)      = lo;    // dup pids write identical data: benign
        *(f4*)(out + 64 + tx * 4) = hi;
    }
}

// ---------------------------------------------------------------------------
// K2: exact top-16 + softmax weights per pair. One wave per pid.
// Lane holds tokens 2*lane, 2*lane+1 -> exact jax tie-break (lowest index).
// ---------------------------------------------------------------------------
__global__ __launch_bounds__(256) void tok_select(const float* __restrict__ scores,
                                                  const float* __restrict__ sel_w,
                                                  int* __restrict__ pvt,
                                                  float* __restrict__ pvw)
{
    const int pid  = blockIdx.x * 4 + (threadIdx.x >> 6);
    const int lane = threadIdx.x & 63;

    float sw = sel_w[pid];
    if (sw == 0.f) {                        // never binned: zero contribution
        if (lane < TOK_K) {
            pvt[(size_t)pid * TOK_K + lane] = 0;
            pvw[(size_t)pid * TOK_K + lane] = 0.f;
        }
        return;
    }

    f2 c = *(const f2*)(scores + (size_t)pid * 128 + lane * 2);
    float c0 = c[0], c1 = c[1];

    float tv[TOK_K];
    int   tt[TOK_K];
    #pragma unroll
    for (int j = 0; j < TOK_K; ++j) {
        float lm = fmaxf(c0, c1);
        float m = lm;
        #pragma unroll
        for (int off = 32; off > 0; off >>= 1) m = fmaxf(m, __shfl_xor(m, off));
        u64 b0 = __ballot(c0 == m);
        u64 b1 = __ballot(c1 == m);
        int L0 = b0 ? (__ffsll(b0) - 1) : 64;
        int L1 = b1 ? (__ffsll(b1) - 1) : 64;
        int t0 = 2 * L0, t1 = 2 * L1 + 1;
        int t  = min(t0, t1);               // lowest token index among ties
        tv[j] = m;
        tt[j] = t;
        if (lane == (t >> 1)) {
            if (t & 1) c1 = NINF; else c0 = NINF;
        }
    }

    float m0 = tv[0];
    float Z = 0.f;
    float pw[TOK_K];
    #pragma unroll
    for (int j = 0; j < TOK_K; ++j) { pw[j] = expf(tv[j] - m0); Z += pw[j]; }
    float cs = sw / Z;                      // fold stat weight in

    if (lane < TOK_K) {
        pvt[(size_t)pid * TOK_K + lane] = tt[lane];
        pvw[(size_t)pid * TOK_K + lane] = pw[lane] * cs;
    }
}

// ---------------------------------------------------------------------------
// K3: PV accumulate over RAW values (Wv folded into M_vo). One wave per (b,q),
// registers only, single plain store (no atomics -> deterministic).
// ---------------------------------------------------------------------------
__global__ __launch_bounds__(256) void tok_pv2(const float* __restrict__ values,
                                               const int* __restrict__ sel_i,
                                               const int* __restrict__ pvt,
                                               const float* __restrict__ pvw,
                                               float* __restrict__ out_pre)
{
    const int bq   = blockIdx.x * 4 + (threadIdx.x >> 6);
    const int lane = threadIdx.x & 63;
    const int b    = bq >> 9;

    float o0 = 0.f, o1 = 0.f;
    #pragma unroll
    for (int si = 0; si < STAT_K; ++si) {
        const int pid = bq * STAT_K + si;
        const int s   = sel_i[pid];
        const float* vb = values + ((size_t)(b * SN + s) << 14);
        const int*   tp = pvt + (size_t)pid * TOK_K;
        const float* wp = pvw + (size_t)pid * TOK_K;
        #pragma unroll
        for (int j = 0; j < TOK_K; ++j) {
            int   t = tp[j];                 // wave-uniform
            float w = wp[j];                 // ==0 for skipped pids: exact no-op
            f2 x = *(const f2*)(vb + (size_t)t * 128 + lane * 2);
            o0 = fmaf(w, x[0], o0);
            o1 = fmaf(w, x[1], o1);
        }
    }
    f2 o = {o0, o1};
    *(f2*)(out_pre + (size_t)bq * 128 + lane * 2) = o;
}

// ---------------------------------------------------------------------------
extern "C" void kernel_launch(void* const* d_in, const int* in_sizes, int n_in,
                              void* d_out, int out_size, void* d_ws, size_t ws_size,
                              hipStream_t stream)
{
    const float* queries    = (const float*)d_in[0];
    const float* stat_keys  = (const float*)d_in[1];
    const float* token_keys = (const float*)d_in[2];
    const float* values     = (const float*)d_in[3];
    const int*   vlen       = (const int*)d_in[4];
    const float* Wq_stat    = (const float*)d_in[5];
    const float* Wq_token   = (const float*)d_in[6];
    const float* Wk_stat    = (const float*)d_in[7];
    const float* Wk_token   = (const float*)d_in[8];
    const float* Wv         = (const float*)d_in[9];
    const float* Wo         = (const float*)d_in[10];

    char* ws = (char*)d_ws;
    float* q_stat  = (float*)(ws);                 // 2 MB (dead after stat_topk)
    int*   list    = (int*)  (ws);                 // 1 MB, overlays q_stat
    float* q_tok   = (float*)(ws + 2097152);       // 2 MB (live till tok_score)
    float* k_stat  = (float*)(ws + 4194304);       // 256 KB (dead after stat_topk)
    int*   cnt     = (int*)  (ws + 4194304);       // 2 KB, overlays k_stat
    float* M_vo    = (float*)(ws + 4456448);       // 64 KB (Wv @ Wo)
    int*   sel_i   = (int*)  (ws + 4521984);       // 128 KB
    float* sel_w   = (float*)(ws + 4653056);       // 128 KB
    float* kT      = (float*)(ws + 4784128);       // 32 MB (dead after tok_score)
    float* scores  = (float*)(ws + 38338560);      // 16 MB
    int*   pvt     = (int*)  (ws + 55115776);      // 2 MB
    float* pvw     = (float*)(ws + 57212928);      // 2 MB
    float* out_pre = (float*)(ws + 59310080);      // 2 MB   (total ~61.4 MB)

    // Projections feeding selection (fp32 exact) + the safe Wv@Wo fold
    proj_all<<<581, 256, 0, stream>>>(queries, stat_keys, token_keys,
                                      Wq_stat, Wq_token, Wk_stat, Wk_token, Wv, Wo,
                                      q_stat, q_tok, k_stat, kT, M_vo);

    // Stat-level top-8 selection + weights
    stat_topk<<<BB * QN, 64, 0, stream>>>(q_stat, k_stat, vlen, sel_i, sel_w);

    // Zero bin counters (overlays dead k_stat), bin (q,si) pairs by stat
    zero_cnt<<<2, 256, 0, stream>>>(cnt);
    bin_build<<<128, 256, 0, stream>>>(sel_i, sel_w, cnt, list);

    // K1: token scores (GEMM shape, k read once per chunk from L2)
    tok_score<<<4096, 256, 0, stream>>>(q_tok, kT, cnt, list, scores);

    // K2: exact top-16 + folded softmax weights, one wave per pair
    tok_select<<<BB * QN * STAT_K / 4, 256, 0, stream>>>(scores, sel_w, pvt, pvw);

    // K3: PV accumulate on RAW values, one wave per (b,q), no atomics
    tok_pv2<<<BB * QN / 4, 256, 0, stream>>>(values, sel_i, pvt, pvw, out_pre);

    // Output projection with folded M_vo
    proj_out<<<64, 256, 0, stream>>>(out_pre, M_vo, (float*)d_out);
}

// Round 9
// 279.355 us; speedup vs baseline: 4.9198x; 4.8593x over previous
//
#include <hip/hip_runtime.h>
#include <hip/hip_bf16.h>
#include <math.h>

// Problem constants (from setup_inputs)
#define BB 8
#define QN 512
#define SN 64
#define TN 128
#define DD 128
#define STAT_K 8
#define TOK_K 16
#define SCALE 0.08838834764831845f   // 1/sqrt(128)
#define NEGBIG -1e6f
#define NINF  -3.4e38f

typedef float f4 __attribute__((ext_vector_type(4)));
typedef float f2 __attribute__((ext_vector_type(2)));
typedef unsigned long long u64;

// ---------------------------------------------------------------------------
// LDS-free GEMM tile (R6-proven, NON-pipelined: 92 VGPR, no spill):
// C[128-row-block] = A @ W. W read from L1/L2 (broadcast, 64 KB).
// 256 threads, 8x8 per-thread tile.
// ---------------------------------------------------------------------------
__device__ __forceinline__ void proj_tile8_g(const float* __restrict__ A,
                                             const float* __restrict__ W,
                                             float* __restrict__ C,
                                             int blk, int transposed, int tid)
{
    const int tx = tid & 15;    // cols tx*4..+3 and 64+tx*4..+3
    const int ty = tid >> 4;    // rows ty*8..+7
    const size_t rowBase = (size_t)blk * 128;
    const float* Ab = A + (rowBase + ty * 8) * 128;

    float acc[8][8];
    #pragma unroll
    for (int i = 0; i < 8; ++i)
        #pragma unroll
        for (int j = 0; j < 8; ++j) acc[i][j] = 0.f;

    #pragma unroll 2
    for (int k0 = 0; k0 < 128; k0 += 4) {
        f4 a[8];
        #pragma unroll
        for (int i = 0; i < 8; ++i)
            a[i] = *(const f4*)(Ab + i * 128 + k0);        // 16-lane broadcast
        f4 wl[4], wh[4];
        #pragma unroll
        for (int kk = 0; kk < 4; ++kk) {
            wl[kk] = *(const f4*)(W + (size_t)(k0 + kk) * 128 + tx * 4);
            wh[kk] = *(const f4*)(W + (size_t)(k0 + kk) * 128 + 64 + tx * 4);
        }
        #pragma unroll
        for (int i = 0; i < 8; ++i)
            #pragma unroll
            for (int kk = 0; kk < 4; ++kk)
                #pragma unroll
                for (int j = 0; j < 4; ++j) {
                    acc[i][j]     = fmaf(a[i][kk], wl[kk][j], acc[i][j]);
                    acc[i][4 + j] = fmaf(a[i][kk], wh[kk][j], acc[i][4 + j]);
                }
    }

    if (!transposed) {
        #pragma unroll
        for (int i = 0; i < 8; ++i) {
            size_t row = rowBase + ty * 8 + i;
            f4 lo = {acc[i][0], acc[i][1], acc[i][2], acc[i][3]};
            f4 hi = {acc[i][4], acc[i][5], acc[i][6], acc[i][7]};
            *(f4*)&C[row * 128 + tx * 4]      = lo;
            *(f4*)&C[row * 128 + 64 + tx * 4] = hi;
        }
    } else {
        float* Cb = C + ((size_t)blk << 14);   // per-(b,s) [d][t] block
        #pragma unroll
        for (int j = 0; j < 4; ++j) {
            int clo = tx * 4 + j;
            int chi = 64 + tx * 4 + j;
            f4 v0 = {acc[0][j], acc[1][j], acc[2][j], acc[3][j]};
            f4 v1 = {acc[4][j], acc[5][j], acc[6][j], acc[7][j]};
            *(f4*)&Cb[clo * 128 + ty * 8]     = v0;
            *(f4*)&Cb[clo * 128 + ty * 8 + 4] = v1;
            f4 v2 = {acc[0][4 + j], acc[1][4 + j], acc[2][4 + j], acc[3][4 + j]};
            f4 v3 = {acc[4][4 + j], acc[5][4 + j], acc[6][4 + j], acc[7][4 + j]};
            *(f4*)&Cb[chi * 128 + ty * 8]     = v2;
            *(f4*)&Cb[chi * 128 + ty * 8 + 4] = v3;
        }
    }
}

// Input projections + the Wv@Wo fold, one launch. values projection is GONE:
// PV runs on raw values and the output projection uses M_vo = Wv @ Wo
// (mathematically identical — combine is linear; no selection risk).
__global__ __launch_bounds__(256) void proj_all(const float* __restrict__ queries,
                                                const float* __restrict__ stat_keys,
                                                const float* __restrict__ token_keys,
                                                const float* __restrict__ Wq_stat,
                                                const float* __restrict__ Wq_token,
                                                const float* __restrict__ Wk_stat,
                                                const float* __restrict__ Wk_token,
                                                const float* __restrict__ Wv,
                                                const float* __restrict__ Wo,
                                                float* __restrict__ q_stat,
                                                float* __restrict__ q_tok,
                                                float* __restrict__ k_stat,
                                                float* __restrict__ kT,
                                                float* __restrict__ M_vo)
{
    const int bi = blockIdx.x;
    if (bi < 512)       proj_tile8_g(token_keys, Wk_token, kT,     bi,       1, threadIdx.x);
    else if (bi < 544)  proj_tile8_g(queries,    Wq_stat,  q_stat, bi - 512, 0, threadIdx.x);
    else if (bi < 576)  proj_tile8_g(queries,    Wq_token, q_tok,  bi - 544, 0, threadIdx.x);
    else if (bi < 580)  proj_tile8_g(stat_keys,  Wk_stat,  k_stat, bi - 576, 0, threadIdx.x);
    else                proj_tile8_g(Wv,         Wo,       M_vo,   0,        0, threadIdx.x);
}

// Output projection: out = out_pre @ M_vo. 64 rows/block.
__global__ __launch_bounds__(256) void proj_out(const float* __restrict__ A,
                                                const float* __restrict__ W,
                                                float* __restrict__ C)
{
    const int tid = threadIdx.x;
    const int tx = tid & 15;
    const int ty = tid >> 4;
    const int rowBase = blockIdx.x * 64 + ty * 4;
    const float* Ab = A + (size_t)rowBase * 128;

    float acc[4][8];
    #pragma unroll
    for (int i = 0; i < 4; ++i)
        #pragma unroll
        for (int j = 0; j < 8; ++j) acc[i][j] = 0.f;

    #pragma unroll 2
    for (int k0 = 0; k0 < 128; k0 += 4) {
        f4 a[4];
        #pragma unroll
        for (int i = 0; i < 4; ++i)
            a[i] = *(const f4*)(Ab + i * 128 + k0);
        f4 wl[4], wh[4];
        #pragma unroll
        for (int kk = 0; kk < 4; ++kk) {
            wl[kk] = *(const f4*)(W + (k0 + kk) * 128 + tx * 4);
            wh[kk] = *(const f4*)(W + (k0 + kk) * 128 + 64 + tx * 4);
        }
        #pragma unroll
        for (int i = 0; i < 4; ++i)
            #pragma unroll
            for (int kk = 0; kk < 4; ++kk)
                #pragma unroll
                for (int j = 0; j < 4; ++j) {
                    acc[i][j]     = fmaf(a[i][kk], wl[kk][j], acc[i][j]);
                    acc[i][4 + j] = fmaf(a[i][kk], wh[kk][j], acc[i][4 + j]);
                }
    }
    #pragma unroll
    for (int i = 0; i < 4; ++i) {
        size_t row = (size_t)rowBase + i;
        f4 lo = {acc[i][0], acc[i][1], acc[i][2], acc[i][3]};
        f4 hi = {acc[i][4], acc[i][5], acc[i][6], acc[i][7]};
        *(f4*)&C[row * 128 + tx * 4]      = lo;
        *(f4*)&C[row * 128 + 64 + tx * 4] = hi;
    }
}

// ---------------------------------------------------------------------------
// Stat level: one wave per (b,q), lane = stat s. Top-8 + softmax (exact jax
// tie-break). Invalid stats -> exp underflows to exactly 0. (proven R1)
// ---------------------------------------------------------------------------
__global__ __launch_bounds__(64, 4) void stat_topk(const float* __restrict__ qs,
                                                   const float* __restrict__ ks,
                                                   const int* __restrict__ vlen,
                                                   int* __restrict__ sel_i,
                                                   float* __restrict__ sel_w)
{
    const int bq   = blockIdx.x;
    const int b    = bq >> 9;
    const int lane = threadIdx.x;

    const f4* q4 = (const f4*)(qs + (size_t)bq * 128);
    const f4* k4 = (const f4*)(ks + (size_t)(b * SN + lane) * 128);
    float acc = 0.f;
    #pragma unroll 8
    for (int kk = 0; kk < 32; ++kk) {
        f4 q = q4[kk];
        f4 k = k4[kk];
        acc = fmaf(q[0], k[0], acc);
        acc = fmaf(q[1], k[1], acc);
        acc = fmaf(q[2], k[2], acc);
        acc = fmaf(q[3], k[3], acc);
    }
    float score = acc * SCALE;
    if (lane >= vlen[b]) score = NEGBIG;

    float work = score;
    float tv[STAT_K];
    int   ti[STAT_K];
    #pragma unroll
    for (int j = 0; j < STAT_K; ++j) {
        float m = work;
        #pragma unroll
        for (int off = 32; off > 0; off >>= 1) m = fmaxf(m, __shfl_xor(m, off));
        unsigned long long ball = __ballot(work == m);
        int L = __ffsll(ball) - 1;     // lowest index wins ties
        tv[j] = m;
        ti[j] = L;
        if (lane == L) work = NINF;
    }

    float w[STAT_K];
    float Z = 0.f;
    #pragma unroll
    for (int j = 0; j < STAT_K; ++j) { w[j] = expf(tv[j] - tv[0]); Z += w[j]; }
    float invZ = 1.f / Z;

    if (lane < STAT_K) {
        sel_i[(size_t)bq * STAT_K + lane] = ti[lane];
        sel_w[(size_t)bq * STAT_K + lane] = w[lane] * invZ;
    }
}

// ---------------------------------------------------------------------------
__global__ void zero_cnt(int* __restrict__ cnt)
{
    int idx = blockIdx.x * 256 + threadIdx.x;
    if (idx < BB * SN) cnt[idx] = 0;
}

__global__ void bin_build(const int* __restrict__ sel_i,
                          const float* __restrict__ sel_w,
                          int* __restrict__ cnt, int* __restrict__ list)
{
    int idx = blockIdx.x * 256 + threadIdx.x;    // bq*8+si, 32768 total
    if (idx >= BB * QN * STAT_K) return;
    float sw = sel_w[idx];
    if (sw == 0.f) return;                       // exactly-zero contribution
    int bq = idx >> 3, si = idx & 7;
    int b = bq >> 9, q = bq & 511;
    int s = sel_i[idx];
    int bs = b * SN + s;
    int pos = atomicAdd(&cnt[bs], 1);
    list[bs * 512 + pos] = q | (si << 16);
}

// ---------------------------------------------------------------------------
// K1: token scores as a plain GEMM (R6-proven body, ~100 VGPR, no spill).
// Block = (bin, 64-pair chunk). scores[pid][t] = q_tok[bq] . kT[bs][.][t]*SCALE
// ---------------------------------------------------------------------------
__global__ __launch_bounds__(256) void tok_score(const float* __restrict__ qt,
                                                 const float* __restrict__ kT,
                                                 const int* __restrict__ cnt,
                                                 const int* __restrict__ list,
                                                 float* __restrict__ scores)
{
    const int bin   = blockIdx.x & 511;
    const int chunk = blockIdx.x >> 9;
    const int b  = bin & 7;            // batch fast -> XCD spread
    const int s  = bin >> 3;
    const int bs = b * SN + s;
    const int nq = cnt[bs];
    const int q0 = chunk * 64;
    if (q0 >= nq) return;

    const int tid = threadIdx.x;
    const int tx = tid & 15;           // t-cols tx*4..+3 and 64+tx*4..+3
    const int ty = tid >> 4;           // pair-slots q0+ty*4..+3

    int pid[4];
    const float* Ab[4];
    #pragma unroll
    for (int i = 0; i < 4; ++i) {
        int e  = list[bs * 512 + min(q0 + ty * 4 + i, nq - 1)];  // clamp: dup pair
        int q  = e & 0xffff;
        int si = (e >> 16) & 7;
        pid[i] = ((b << 9) + q) * 8 + si;
        Ab[i]  = qt + ((size_t)(b << 9) + q) * 128;
    }
    const float* kb = kT + ((size_t)bs << 14);

    float acc[4][8];
    #pragma unroll
    for (int i = 0; i < 4; ++i)
        #pragma unroll
        for (int j = 0; j < 8; ++j) acc[i][j] = 0.f;

    #pragma unroll 2
    for (int k0 = 0; k0 < 128; k0 += 4) {
        f4 a[4];
        #pragma unroll
        for (int i = 0; i < 4; ++i)
            a[i] = *(const f4*)(Ab[i] + k0);               // 16-lane broadcast
        f4 wl[4], wh[4];
        #pragma unroll
        for (int kk = 0; kk < 4; ++kk) {
            wl[kk] = *(const f4*)(kb + (size_t)(k0 + kk) * 128 + tx * 4);
            wh[kk] = *(const f4*)(kb + (size_t)(k0 + kk) * 128 + 64 + tx * 4);
        }
        #pragma unroll
        for (int i = 0; i < 4; ++i)
            #pragma unroll
            for (int kk = 0; kk < 4; ++kk)
                #pragma unroll
                for (int j = 0; j < 4; ++j) {
                    acc[i][j]     = fmaf(a[i][kk], wl[kk][j], acc[i][j]);
                    acc[i][4 + j] = fmaf(a[i][kk], wh[kk][j], acc[i][4 + j]);
                }
    }

    #pragma unroll
    for (int i = 0; i < 4; ++i) {
        float* out = scores + (size_t)pid[i] * 128;
        f4 lo = {acc[i][0] * SCALE, acc[i][1] * SCALE, acc[i][2] * SCALE, acc[i][3] * SCALE};
        f4 hi = {acc[i][4] * SCALE, acc[i][5] * SCALE, acc[i][6] * SCALE, acc[i][7] * SCALE};
        *(f4*)(out + tx * 4)      = lo;    // dup pids write identical data: benign
        *(f4*)(out + 64 + tx * 4) = hi;
    }
}

// ---------------------------------------------------------------------------
// K2: exact top-16 + softmax weights per pair. One wave per pid.
// Lane holds tokens 2*lane, 2*lane+1 -> exact jax tie-break (lowest index).
// ---------------------------------------------------------------------------
__global__ __launch_bounds__(256) void tok_select(const float* __restrict__ scores,
                                                  const float* __restrict__ sel_w,
                                                  int* __restrict__ pvt,
                                                  float* __restrict__ pvw)
{
    const int pid  = blockIdx.x * 4 + (threadIdx.x >> 6);
    const int lane = threadIdx.x & 63;

    float sw = sel_w[pid];
    if (sw == 0.f) {                        // never binned: zero contribution
        if (lane < TOK_K) {
            pvt[(size_t)pid * TOK_K + lane] = 0;
            pvw[(size_t)pid * TOK_K + lane] = 0.f;
        }
        return;
    }

    f2 c = *(const f2*)(scores + (size_t)pid * 128 + lane * 2);
    float c0 = c[0], c1 = c[1];

    float tv[TOK_K];
    int   tt[TOK_K];
    #pragma unroll
    for (int j = 0; j < TOK_K; ++j) {
        float lm = fmaxf(c0, c1);
        float m = lm;
        #pragma unroll
        for (int off = 32; off > 0; off >>= 1) m = fmaxf(m, __shfl_xor(m, off));
        u64 b0 = __ballot(c0 == m);
        u64 b1 = __ballot(c1 == m);
        int L0 = b0 ? (__ffsll(b0) - 1) : 64;
        int L1 = b1 ? (__ffsll(b1) - 1) : 64;
        int t0 = 2 * L0, t1 = 2 * L1 + 1;
        int t  = min(t0, t1);               // lowest token index among ties
        tv[j] = m;
        tt[j] = t;
        if (lane == (t >> 1)) {
            if (t & 1) c1 = NINF; else c0 = NINF;
        }
    }

    float m0 = tv[0];
    float Z = 0.f;
    float pw[TOK_K];
    #pragma unroll
    for (int j = 0; j < TOK_K; ++j) { pw[j] = expf(tv[j] - m0); Z += pw[j]; }
    float cs = sw / Z;                      // fold stat weight in

    if (lane < TOK_K) {
        pvt[(size_t)pid * TOK_K + lane] = tt[lane];
        pvw[(size_t)pid * TOK_K + lane] = pw[lane] * cs;
    }
}

// ---------------------------------------------------------------------------
// K3: PV accumulate over RAW values (Wv folded into M_vo). One wave per (b,q),
// registers only, single plain store (no atomics -> deterministic).
// ---------------------------------------------------------------------------
__global__ __launch_bounds__(256) void tok_pv2(const float* __restrict__ values,
                                               const int* __restrict__ sel_i,
                                               const int* __restrict__ pvt,
                                               const float* __restrict__ pvw,
                                               float* __restrict__ out_pre)
{
    const int bq   = blockIdx.x * 4 + (threadIdx.x >> 6);
    const int lane = threadIdx.x & 63;
    const int b    = bq >> 9;

    float o0 = 0.f, o1 = 0.f;
    #pragma unroll
    for (int si = 0; si < STAT_K; ++si) {
        const int pid = bq * STAT_K + si;
        const int s   = sel_i[pid];
        const float* vb = values + ((size_t)(b * SN + s) << 14);
        const int*   tp = pvt + (size_t)pid * TOK_K;
        const float* wp = pvw + (size_t)pid * TOK_K;
        #pragma unroll
        for (int j = 0; j < TOK_K; ++j) {
            int   t = tp[j];                 // wave-uniform
            float w = wp[j];                 // ==0 for skipped pids: exact no-op
            f2 x = *(const f2*)(vb + (size_t)t * 128 + lane * 2);
            o0 = fmaf(w, x[0], o0);
            o1 = fmaf(w, x[1], o1);
        }
    }
    f2 o = {o0, o1};
    *(f2*)(out_pre + (size_t)bq * 128 + lane * 2) = o;
}

// ---------------------------------------------------------------------------
extern "C" void kernel_launch(void* const* d_in, const int* in_sizes, int n_in,
                              void* d_out, int out_size, void* d_ws, size_t ws_size,
                              hipStream_t stream)
{
    const float* queries    = (const float*)d_in[0];
    const float* stat_keys  = (const float*)d_in[1];
    const float* token_keys = (const float*)d_in[2];
    const float* values     = (const float*)d_in[3];
    const int*   vlen       = (const int*)d_in[4];
    const float* Wq_stat    = (const float*)d_in[5];
    const float* Wq_token   = (const float*)d_in[6];
    const float* Wk_stat    = (const float*)d_in[7];
    const float* Wk_token   = (const float*)d_in[8];
    const float* Wv         = (const float*)d_in[9];
    const float* Wo         = (const float*)d_in[10];

    char* ws = (char*)d_ws;
    float* q_stat  = (float*)(ws);                 // 2 MB (dead after stat_topk)
    int*   list    = (int*)  (ws);                 // 1 MB, overlays q_stat
    float* q_tok   = (float*)(ws + 2097152);       // 2 MB (live till tok_score)
    float* k_stat  = (float*)(ws + 4194304);       // 256 KB (dead after stat_topk)
    int*   cnt     = (int*)  (ws + 4194304);       // 2 KB, overlays k_stat
    float* M_vo    = (float*)(ws + 4456448);       // 64 KB (Wv @ Wo)
    int*   sel_i   = (int*)  (ws + 4521984);       // 128 KB
    float* sel_w   = (float*)(ws + 4653056);       // 128 KB
    float* kT      = (float*)(ws + 4784128);       // 32 MB (dead after tok_score)
    float* scores  = (float*)(ws + 38338560);      // 16 MB
    int*   pvt     = (int*)  (ws + 55115776);      // 2 MB
    float* pvw     = (float*)(ws + 57212928);      // 2 MB
    float* out_pre = (float*)(ws + 59310080);      // 2 MB   (total ~61.4 MB)

    // Projections feeding selection (fp32 exact) + the safe Wv@Wo fold
    proj_all<<<581, 256, 0, stream>>>(queries, stat_keys, token_keys,
                                      Wq_stat, Wq_token, Wk_stat, Wk_token, Wv, Wo,
                                      q_stat, q_tok, k_stat, kT, M_vo);

    // Stat-level top-8 selection + weights
    stat_topk<<<BB * QN, 64, 0, stream>>>(q_stat, k_stat, vlen, sel_i, sel_w);

    // Zero bin counters (overlays dead k_stat), bin (q,si) pairs by stat
    zero_cnt<<<2, 256, 0, stream>>>(cnt);
    bin_build<<<128, 256, 0, stream>>>(sel_i, sel_w, cnt, list);

    // K1: token scores (GEMM shape, k read once per chunk from L2)
    tok_score<<<4096, 256, 0, stream>>>(q_tok, kT, cnt, list, scores);

    // K2: exact top-16 + folded softmax weights, one wave per pair
    tok_select<<<BB * QN * STAT_K / 4, 256, 0, stream>>>(scores, sel_w, pvt, pvw);

    // K3: PV accumulate on RAW values, one wave per (b,q), no atomics
    tok_pv2<<<BB * QN / 4, 256, 0, stream>>>(values, sel_i, pvt, pvw, out_pre);

    // Output projection with folded M_vo
    proj_out<<<64, 256, 0, stream>>>(out_pre, M_vo, (float*)d_out);
}

// Round 10
// 253.452 us; speedup vs baseline: 5.4226x; 1.1022x over previous
//
#include <hip/hip_runtime.h>
#include <hip/hip_bf16.h>
#include <math.h>

// Problem constants (from setup_inputs)
#define BB 8
#define QN 512
#define SN 64
#define TN 128
#define DD 128
#define STAT_K 8
#define TOK_K 16
#define SCALE 0.08838834764831845f   // 1/sqrt(128)
#define NEGBIG -1e6f
#define NINF  -3.4e38f

typedef float f4 __attribute__((ext_vector_type(4)));
typedef float f2 __attribute__((ext_vector_type(2)));
typedef unsigned long long u64;

// ---------------------------------------------------------------------------
// LDS-free GEMM tile, 4 rows/thread (64-row blocks, 256 threads, acc[4][8]).
// W read from L1/L2 (broadcast, 64 KB, cache-resident). ~70 VGPR, no spill.
// transposed: rows are token-rows of [512 bins x 128 tokens]; a 64-row tile
// sits wholly inside one bin -> Cb = C + (rowBase>>7)<<14, col-major store.
// ---------------------------------------------------------------------------
__device__ __forceinline__ void proj_tile4_g(const float* __restrict__ A,
                                             const float* __restrict__ W,
                                             float* __restrict__ C,
                                             int rowBase, int transposed, int tid)
{
    const int tx = tid & 15;    // cols tx*4..+3 and 64+tx*4..+3
    const int ty = tid >> 4;    // 0..15, rows ty*4..+3
    const float* Ab = A + (size_t)(rowBase + ty * 4) * 128;

    float acc[4][8];
    #pragma unroll
    for (int i = 0; i < 4; ++i)
        #pragma unroll
        for (int j = 0; j < 8; ++j) acc[i][j] = 0.f;

    #pragma unroll 2
    for (int k0 = 0; k0 < 128; k0 += 4) {
        f4 a[4];
        #pragma unroll
        for (int i = 0; i < 4; ++i)
            a[i] = *(const f4*)(Ab + i * 128 + k0);        // 16-lane broadcast
        f4 wl[4], wh[4];
        #pragma unroll
        for (int kk = 0; kk < 4; ++kk) {
            wl[kk] = *(const f4*)(W + (size_t)(k0 + kk) * 128 + tx * 4);
            wh[kk] = *(const f4*)(W + (size_t)(k0 + kk) * 128 + 64 + tx * 4);
        }
        #pragma unroll
        for (int i = 0; i < 4; ++i)
            #pragma unroll
            for (int kk = 0; kk < 4; ++kk)
                #pragma unroll
                for (int j = 0; j < 4; ++j) {
                    acc[i][j]     = fmaf(a[i][kk], wl[kk][j], acc[i][j]);
                    acc[i][4 + j] = fmaf(a[i][kk], wh[kk][j], acc[i][4 + j]);
                }
    }

    if (!transposed) {
        #pragma unroll
        for (int i = 0; i < 4; ++i) {
            size_t row = (size_t)rowBase + ty * 4 + i;
            f4 lo = {acc[i][0], acc[i][1], acc[i][2], acc[i][3]};
            f4 hi = {acc[i][4], acc[i][5], acc[i][6], acc[i][7]};
            *(f4*)&C[row * 128 + tx * 4]      = lo;
            *(f4*)&C[row * 128 + 64 + tx * 4] = hi;
        }
    } else {
        float* Cb = C + ((size_t)(rowBase >> 7) << 14);    // bin base
        const int rb = (rowBase & 127) + ty * 4;           // row within bin
        #pragma unroll
        for (int j = 0; j < 4; ++j) {
            int clo = tx * 4 + j;
            int chi = 64 + tx * 4 + j;
            f4 v0 = {acc[0][j], acc[1][j], acc[2][j], acc[3][j]};
            f4 v1 = {acc[0][4 + j], acc[1][4 + j], acc[2][4 + j], acc[3][4 + j]};
            *(f4*)&Cb[clo * 128 + rb] = v0;
            *(f4*)&Cb[chi * 128 + rb] = v1;
        }
    }
}

// Input projections + the Wv@Wo fold, one launch, 64-row tiles (1162 blocks).
// values projection is GONE: PV runs on raw values; out-proj uses M_vo=Wv@Wo.
__global__ __launch_bounds__(256) void proj_all(const float* __restrict__ queries,
                                                const float* __restrict__ stat_keys,
                                                const float* __restrict__ token_keys,
                                                const float* __restrict__ Wq_stat,
                                                const float* __restrict__ Wq_token,
                                                const float* __restrict__ Wk_stat,
                                                const float* __restrict__ Wk_token,
                                                const float* __restrict__ Wv,
                                                const float* __restrict__ Wo,
                                                float* __restrict__ q_stat,
                                                float* __restrict__ q_tok,
                                                float* __restrict__ k_stat,
                                                float* __restrict__ kT,
                                                float* __restrict__ M_vo)
{
    const int bi = blockIdx.x;
    if (bi < 1024)       proj_tile4_g(token_keys, Wk_token, kT,     bi * 64,           1, threadIdx.x);
    else if (bi < 1088)  proj_tile4_g(queries,    Wq_stat,  q_stat, (bi - 1024) * 64,  0, threadIdx.x);
    else if (bi < 1152)  proj_tile4_g(queries,    Wq_token, q_tok,  (bi - 1088) * 64,  0, threadIdx.x);
    else if (bi < 1160)  proj_tile4_g(stat_keys,  Wk_stat,  k_stat, (bi - 1152) * 64,  0, threadIdx.x);
    else                 proj_tile4_g(Wv,         Wo,       M_vo,   (bi - 1160) * 64,  0, threadIdx.x);
}

// Output projection: out = out_pre @ M_vo. 64 rows/block.
__global__ __launch_bounds__(256) void proj_out(const float* __restrict__ A,
                                                const float* __restrict__ W,
                                                float* __restrict__ C)
{
    proj_tile4_g(A, W, C, blockIdx.x * 64, 0, threadIdx.x);
}

// ---------------------------------------------------------------------------
// Stat level: one wave per (b,q), lane = stat s. Top-8 + softmax (exact jax
// tie-break). Invalid stats -> exp underflows to exactly 0. (proven R1)
// ---------------------------------------------------------------------------
__global__ __launch_bounds__(64, 4) void stat_topk(const float* __restrict__ qs,
                                                   const float* __restrict__ ks,
                                                   const int* __restrict__ vlen,
                                                   int* __restrict__ sel_i,
                                                   float* __restrict__ sel_w)
{
    const int bq   = blockIdx.x;
    const int b    = bq >> 9;
    const int lane = threadIdx.x;

    const f4* q4 = (const f4*)(qs + (size_t)bq * 128);
    const f4* k4 = (const f4*)(ks + (size_t)(b * SN + lane) * 128);
    float acc = 0.f;
    #pragma unroll 8
    for (int kk = 0; kk < 32; ++kk) {
        f4 q = q4[kk];
        f4 k = k4[kk];
        acc = fmaf(q[0], k[0], acc);
        acc = fmaf(q[1], k[1], acc);
        acc = fmaf(q[2], k[2], acc);
        acc = fmaf(q[3], k[3], acc);
    }
    float score = acc * SCALE;
    if (lane >= vlen[b]) score = NEGBIG;

    float work = score;
    float tv[STAT_K];
    int   ti[STAT_K];
    #pragma unroll
    for (int j = 0; j < STAT_K; ++j) {
        float m = work;
        #pragma unroll
        for (int off = 32; off > 0; off >>= 1) m = fmaxf(m, __shfl_xor(m, off));
        unsigned long long ball = __ballot(work == m);
        int L = __ffsll(ball) - 1;     // lowest index wins ties
        tv[j] = m;
        ti[j] = L;
        if (lane == L) work = NINF;
    }

    float w[STAT_K];
    float Z = 0.f;
    #pragma unroll
    for (int j = 0; j < STAT_K; ++j) { w[j] = expf(tv[j] - tv[0]); Z += w[j]; }
    float invZ = 1.f / Z;

    if (lane < STAT_K) {
        sel_i[(size_t)bq * STAT_K + lane] = ti[lane];
        sel_w[(size_t)bq * STAT_K + lane] = w[lane] * invZ;
    }
}

// ---------------------------------------------------------------------------
__global__ void zero_cnt(int* __restrict__ cnt)
{
    int idx = blockIdx.x * 256 + threadIdx.x;
    if (idx < BB * SN) cnt[idx] = 0;
}

__global__ void bin_build(const int* __restrict__ sel_i,
                          const float* __restrict__ sel_w,
                          int* __restrict__ cnt, int* __restrict__ list)
{
    int idx = blockIdx.x * 256 + threadIdx.x;    // bq*8+si, 32768 total
    if (idx >= BB * QN * STAT_K) return;
    float sw = sel_w[idx];
    if (sw == 0.f) return;                       // exactly-zero contribution
    int bq = idx >> 3, si = idx & 7;
    int b = bq >> 9, q = bq & 511;
    int s = sel_i[idx];
    int bs = b * SN + s;
    int pos = atomicAdd(&cnt[bs], 1);
    list[bs * 512 + pos] = q | (si << 16);
}

// ---------------------------------------------------------------------------
// K1: token scores as a plain GEMM, t-split for occupancy: block =
// (bin, 64-pair chunk, t-half). acc[4][4] = 16 regs, ~70 VGPR, no spill.
// scores[pid][thal*64 + t'] = q_tok[bq] . kT[bs][.][thal*64+t'] * SCALE
// ---------------------------------------------------------------------------
__global__ __launch_bounds__(256) void tok_score(const float* __restrict__ qt,
                                                 const float* __restrict__ kT,
                                                 const int* __restrict__ cnt,
                                                 const int* __restrict__ list,
                                                 float* __restrict__ scores)
{
    const int bin  = blockIdx.x & 511;
    const int rest = blockIdx.x >> 9;  // 0..15
    const int chunk = rest >> 1;
    const int thal  = rest & 1;
    const int b  = bin & 7;            // batch fast -> XCD spread
    const int s  = bin >> 3;
    const int bs = b * SN + s;
    const int nq = cnt[bs];
    const int q0 = chunk * 64;
    if (q0 >= nq) return;

    const int tid = threadIdx.x;
    const int tx = tid & 15;           // t-cols (within half) tx*4..+3
    const int ty = tid >> 4;           // pair-slots q0+ty*4..+3

    int pid[4];
    const float* Ab[4];
    #pragma unroll
    for (int i = 0; i < 4; ++i) {
        int e  = list[bs * 512 + min(q0 + ty * 4 + i, nq - 1)];  // clamp: dup pair
        int q  = e & 0xffff;
        int si = (e >> 16) & 7;
        pid[i] = ((b << 9) + q) * 8 + si;
        Ab[i]  = qt + ((size_t)(b << 9) + q) * 128;
    }
    const float* kb = kT + ((size_t)bs << 14) + thal * 64;

    float acc[4][4];
    #pragma unroll
    for (int i = 0; i < 4; ++i)
        #pragma unroll
        for (int j = 0; j < 4; ++j) acc[i][j] = 0.f;

    #pragma unroll 2
    for (int k0 = 0; k0 < 128; k0 += 4) {
        f4 a[4];
        #pragma unroll
        for (int i = 0; i < 4; ++i)
            a[i] = *(const f4*)(Ab[i] + k0);               // 16-lane broadcast
        f4 wl[4];
        #pragma unroll
        for (int kk = 0; kk < 4; ++kk)
            wl[kk] = *(const f4*)(kb + (size_t)(k0 + kk) * 128 + tx * 4);
        #pragma unroll
        for (int i = 0; i < 4; ++i)
            #pragma unroll
            for (int kk = 0; kk < 4; ++kk)
                #pragma unroll
                for (int j = 0; j < 4; ++j)
                    acc[i][j] = fmaf(a[i][kk], wl[kk][j], acc[i][j]);
    }

    #pragma unroll
    for (int i = 0; i < 4; ++i) {
        f4 o = {acc[i][0] * SCALE, acc[i][1] * SCALE, acc[i][2] * SCALE, acc[i][3] * SCALE};
        *(f4*)(scores + (size_t)pid[i] * 128 + thal * 64 + tx * 4) = o;  // dup pids: identical data
    }
}

// ---------------------------------------------------------------------------
// K2: exact top-16 + softmax weights per pair. One wave per pid.
// Lane holds tokens 2*lane, 2*lane+1 -> exact jax tie-break (lowest index).
// ---------------------------------------------------------------------------
__global__ __launch_bounds__(256) void tok_select(const float* __restrict__ scores,
                                                  const float* __restrict__ sel_w,
                                                  int* __restrict__ pvt,
                                                  float* __restrict__ pvw)
{
    const int pid  = blockIdx.x * 4 + (threadIdx.x >> 6);
    const int lane = threadIdx.x & 63;

    float sw = sel_w[pid];
    if (sw == 0.f) {                        // never binned: zero contribution
        if (lane < TOK_K) {
            pvt[(size_t)pid * TOK_K + lane] = 0;
            pvw[(size_t)pid * TOK_K + lane] = 0.f;
        }
        return;
    }

    f2 c = *(const f2*)(scores + (size_t)pid * 128 + lane * 2);
    float c0 = c[0], c1 = c[1];

    float tv[TOK_K];
    int   tt[TOK_K];
    #pragma unroll
    for (int j = 0; j < TOK_K; ++j) {
        float lm = fmaxf(c0, c1);
        float m = lm;
        #pragma unroll
        for (int off = 32; off > 0; off >>= 1) m = fmaxf(m, __shfl_xor(m, off));
        u64 b0 = __ballot(c0 == m);
        u64 b1 = __ballot(c1 == m);
        int L0 = b0 ? (__ffsll(b0) - 1) : 64;
        int L1 = b1 ? (__ffsll(b1) - 1) : 64;
        int t0 = 2 * L0, t1 = 2 * L1 + 1;
        int t  = min(t0, t1);               // lowest token index among ties
        tv[j] = m;
        tt[j] = t;
        if (lane == (t >> 1)) {
            if (t & 1) c1 = NINF; else c0 = NINF;
        }
    }

    float m0 = tv[0];
    float Z = 0.f;
    float pw[TOK_K];
    #pragma unroll
    for (int j = 0; j < TOK_K; ++j) { pw[j] = expf(tv[j] - m0); Z += pw[j]; }
    float cs = sw / Z;                      // fold stat weight in

    if (lane < TOK_K) {
        pvt[(size_t)pid * TOK_K + lane] = tt[lane];
        pvw[(size_t)pid * TOK_K + lane] = pw[lane] * cs;
    }
}

// ---------------------------------------------------------------------------
// K3: PV accumulate over RAW values (Wv folded into M_vo). One wave per (b,q),
// registers only, single plain store (no atomics -> deterministic).
// ---------------------------------------------------------------------------
__global__ __launch_bounds__(256) void tok_pv2(const float* __restrict__ values,
                                               const int* __restrict__ sel_i,
                                               const int* __restrict__ pvt,
                                               const float* __restrict__ pvw,
                                               float* __restrict__ out_pre)
{
    const int bq   = blockIdx.x * 4 + (threadIdx.x >> 6);
    const int lane = threadIdx.x & 63;
    const int b    = bq >> 9;

    float o0 = 0.f, o1 = 0.f;
    #pragma unroll
    for (int si = 0; si < STAT_K; ++si) {
        const int pid = bq * STAT_K + si;
        const int s   = sel_i[pid];
        const float* vb = values + ((size_t)(b * SN + s) << 14);
        const int*   tp = pvt + (size_t)pid * TOK_K;
        const float* wp = pvw + (size_t)pid * TOK_K;
        #pragma unroll
        for (int j = 0; j < TOK_K; ++j) {
            int   t = tp[j];                 // wave-uniform
            float w = wp[j];                 // ==0 for skipped pids: exact no-op
            f2 x = *(const f2*)(vb + (size_t)t * 128 + lane * 2);
            o0 = fmaf(w, x[0], o0);
            o1 = fmaf(w, x[1], o1);
        }
    }
    f2 o = {o0, o1};
    *(f2*)(out_pre + (size_t)bq * 128 + lane * 2) = o;
}

// ---------------------------------------------------------------------------
extern "C" void kernel_launch(void* const* d_in, const int* in_sizes, int n_in,
                              void* d_out, int out_size, void* d_ws, size_t ws_size,
                              hipStream_t stream)
{
    const float* queries    = (const float*)d_in[0];
    const float* stat_keys  = (const float*)d_in[1];
    const float* token_keys = (const float*)d_in[2];
    const float* values     = (const float*)d_in[3];
    const int*   vlen       = (const int*)d_in[4];
    const float* Wq_stat    = (const float*)d_in[5];
    const float* Wq_token   = (const float*)d_in[6];
    const float* Wk_stat    = (const float*)d_in[7];
    const float* Wk_token   = (const float*)d_in[8];
    const float* Wv         = (const float*)d_in[9];
    const float* Wo         = (const float*)d_in[10];

    char* ws = (char*)d_ws;
    float* q_stat  = (float*)(ws);                 // 2 MB (dead after stat_topk)
    int*   list    = (int*)  (ws);                 // 1 MB, overlays q_stat
    float* q_tok   = (float*)(ws + 2097152);       // 2 MB (live till tok_score)
    float* k_stat  = (float*)(ws + 4194304);       // 256 KB (dead after stat_topk)
    int*   cnt     = (int*)  (ws + 4194304);       // 2 KB, overlays k_stat
    float* M_vo    = (float*)(ws + 4456448);       // 64 KB (Wv @ Wo)
    int*   sel_i   = (int*)  (ws + 4521984);       // 128 KB
    float* sel_w   = (float*)(ws + 4653056);       // 128 KB
    float* kT      = (float*)(ws + 4784128);       // 32 MB (dead after tok_score)
    float* scores  = (float*)(ws + 38338560);      // 16 MB
    int*   pvt     = (int*)  (ws + 55115776);      // 2 MB
    float* pvw     = (float*)(ws + 57212928);      // 2 MB
    float* out_pre = (float*)(ws + 59310080);      // 2 MB   (total ~61.4 MB)

    // Projections feeding selection (fp32 exact) + the safe Wv@Wo fold
    proj_all<<<1162, 256, 0, stream>>>(queries, stat_keys, token_keys,
                                       Wq_stat, Wq_token, Wk_stat, Wk_token, Wv, Wo,
                                       q_stat, q_tok, k_stat, kT, M_vo);

    // Stat-level top-8 selection + weights
    stat_topk<<<BB * QN, 64, 0, stream>>>(q_stat, k_stat, vlen, sel_i, sel_w);

    // Zero bin counters (overlays dead k_stat), bin (q,si) pairs by stat
    zero_cnt<<<2, 256, 0, stream>>>(cnt);
    bin_build<<<128, 256, 0, stream>>>(sel_i, sel_w, cnt, list);

    // K1: token scores (GEMM shape, t-split, k read from L2/L3)
    tok_score<<<8192, 256, 0, stream>>>(q_tok, kT, cnt, list, scores);

    // K2: exact top-16 + folded softmax weights, one wave per pair
    tok_select<<<BB * QN * STAT_K / 4, 256, 0, stream>>>(scores, sel_w, pvt, pvw);

    // K3: PV accumulate on RAW values, one wave per (b,q), no atomics
    tok_pv2<<<BB * QN / 4, 256, 0, stream>>>(values, sel_i, pvt, pvw, out_pre);

    // Output projection with folded M_vo
    proj_out<<<64, 256, 0, stream>>>(out_pre, M_vo, (float*)d_out);
}